// Round 5
// baseline (521.768 us; speedup 1.0000x reference)
//
#include <hip/hip_runtime.h>
#include <hip/hip_bf16.h>

#define NN      50000
#define EE      800000
#define ETOT    (EE + NN)        // + self loops
#define GG      64
#define HEADS   4
#define HID     25
#define DENSE   100
#define IN_DIM  128
#define OUT_DIM 2
#define NPC     5
#define NUM_PROT (OUT_DIM * NPC)
#define NCHUNK  ((NN + 255) / 256)

#define NEG_INF (-3.402823466e38f)

// ---------------- CSR build ----------------
__global__ void k_count(const int* __restrict__ ei, int* __restrict__ cnt, int* __restrict__ pos) {
    int e = blockIdx.x * blockDim.x + threadIdx.x;
    if (e >= ETOT) return;
    int dst = (e < EE) ? ei[EE + e] : (e - EE);
    pos[e] = atomicAdd(&cnt[dst], 1);
}

__global__ void k_scan1(const int* __restrict__ cnt, int* __restrict__ csum) {
    __shared__ int sh[256];
    int i = blockIdx.x * 256 + threadIdx.x;
    int v = (i < NN) ? cnt[i] : 0;
    sh[threadIdx.x] = v;
    __syncthreads();
    for (int s = 128; s > 0; s >>= 1) {
        if (threadIdx.x < s) sh[threadIdx.x] += sh[threadIdx.x + s];
        __syncthreads();
    }
    if (threadIdx.x == 0) csum[blockIdx.x] = sh[0];
}

__global__ void k_scan2(int* __restrict__ csum) {
    __shared__ int sh[256];
    int tid = threadIdx.x;
    int v = (tid < NCHUNK) ? csum[tid] : 0;
    sh[tid] = v;
    __syncthreads();
    for (int s = 1; s < 256; s <<= 1) {
        int t = (tid >= s) ? sh[tid - s] : 0;
        __syncthreads();
        sh[tid] += t;
        __syncthreads();
    }
    if (tid < NCHUNK) csum[tid] = sh[tid] - v;     // exclusive
    if (tid == NCHUNK) csum[NCHUNK] = sh[255];     // total
}

__global__ void k_scan3(const int* __restrict__ cnt, const int* __restrict__ csum, int* __restrict__ offs) {
    __shared__ int sh[256];
    int i = blockIdx.x * 256 + threadIdx.x;
    int v = (i < NN) ? cnt[i] : 0;
    sh[threadIdx.x] = v;
    __syncthreads();
    for (int s = 1; s < 256; s <<= 1) {
        int t = (threadIdx.x >= s) ? sh[threadIdx.x - s] : 0;
        __syncthreads();
        sh[threadIdx.x] += t;
        __syncthreads();
    }
    int excl = sh[threadIdx.x] - v + csum[blockIdx.x];
    if (i <= NN) offs[i] = excl;
}

__global__ void k_scatter(const int* __restrict__ ei, const int* __restrict__ offs,
                          const int* __restrict__ pos, int* __restrict__ csr) {
    int e = blockIdx.x * blockDim.x + threadIdx.x;
    if (e >= ETOT) return;
    int src, dst;
    if (e < EE) { src = ei[e]; dst = ei[EE + e]; }
    else        { src = dst = e - EE; }
    csr[offs[dst] + pos[e]] = src;
}

// ---------------- graph boundaries (batch is sorted) ----------------
__global__ void k_bounds(const int* __restrict__ batch, int* __restrict__ gstart) {
    int n = blockIdx.x * blockDim.x + threadIdx.x;
    if (n >= NN) return;
    int b = batch[n];
    if (n == 0) {
        for (int g = 0; g <= b; g++) gstart[g] = 0;
    } else {
        int pb = batch[n - 1];
        for (int g = pb + 1; g <= b; g++) gstart[g] = n;
    }
    if (n == NN - 1) {
        for (int g = b + 1; g <= GG; g++) gstart[g] = NN;
    }
}

// ---------------- GEMM: H = X @ W  ([N,DIN] x [DIN,100]) ----------------
// 256 threads, 128 rows/block, 16 rows x 4 cols per thread.
template <int DIN, int KC>
__global__ __launch_bounds__(256) void k_gemm(const float* __restrict__ X,
                                              const float* __restrict__ W,
                                              float* __restrict__ H) {
    constexpr int XSTR = KC + 4;          // row stride in floats (16B-aligned, bank-skewed)
    __shared__ float Ws[KC * 104];        // pad 100 -> 104
    __shared__ float Xs[128 * XSTR];
    const int tid = threadIdx.x;
    const int rl = tid >> 5;    // 0..7  -> rows rl*16 .. rl*16+15
    const int cg = tid & 31;    // 0..31 (25 active)
    const int node0 = blockIdx.x * 128;

    float acc[16][4] = {};
    constexpr int NCH = DIN / KC;         // exact: 128/32, 100/20
    constexpr int KQ = KC / 4;
    for (int kb = 0; kb < NCH; ++kb) {
        const int k0 = kb * KC;
        for (int idx = tid; idx < KC * 100; idx += 256) {
            int k = idx / 100, c = idx - k * 100;
            Ws[k * 104 + c] = W[(k0 + k) * 100 + c];
        }
        for (int q = tid; q < 128 * KQ; q += 256) {
            int r = q / KQ, kq = q - r * KQ;
            int row = node0 + r;
            float4 v = {0.f, 0.f, 0.f, 0.f};
            if (row < NN) v = *reinterpret_cast<const float4*>(&X[(size_t)row * DIN + k0 + kq * 4]);
            *reinterpret_cast<float4*>(&Xs[r * XSTR + kq * 4]) = v;
        }
        __syncthreads();
        if (cg < 25) {
            for (int kq = 0; kq < KQ; ++kq) {
                float4 w0 = *reinterpret_cast<const float4*>(&Ws[(kq * 4 + 0) * 104 + cg * 4]);
                float4 w1 = *reinterpret_cast<const float4*>(&Ws[(kq * 4 + 1) * 104 + cg * 4]);
                float4 w2 = *reinterpret_cast<const float4*>(&Ws[(kq * 4 + 2) * 104 + cg * 4]);
                float4 w3 = *reinterpret_cast<const float4*>(&Ws[(kq * 4 + 3) * 104 + cg * 4]);
                #pragma unroll
                for (int j = 0; j < 16; ++j) {
                    float4 xv = *reinterpret_cast<const float4*>(&Xs[(rl * 16 + j) * XSTR + kq * 4]);
                    acc[j][0] += xv.x * w0.x; acc[j][1] += xv.x * w0.y;
                    acc[j][2] += xv.x * w0.z; acc[j][3] += xv.x * w0.w;
                    acc[j][0] += xv.y * w1.x; acc[j][1] += xv.y * w1.y;
                    acc[j][2] += xv.y * w1.z; acc[j][3] += xv.y * w1.w;
                    acc[j][0] += xv.z * w2.x; acc[j][1] += xv.z * w2.y;
                    acc[j][2] += xv.z * w2.z; acc[j][3] += xv.z * w2.w;
                    acc[j][0] += xv.w * w3.x; acc[j][1] += xv.w * w3.y;
                    acc[j][2] += xv.w * w3.z; acc[j][3] += xv.w * w3.w;
                }
            }
        }
        __syncthreads();
    }
    if (cg < 25) {
        #pragma unroll
        for (int j = 0; j < 16; ++j) {
            int row = node0 + rl * 16 + j;
            if (row < NN) {
                float4 v = {acc[j][0], acc[j][1], acc[j][2], acc[j][3]};
                *reinterpret_cast<float4*>(&H[(size_t)row * 100 + cg * 4]) = v;
            }
        }
    }
}

// ---------------- per-node attention logits: es/ed ----------------
__global__ void k_esed(const float* __restrict__ H, const float* __restrict__ AS,
                       const float* __restrict__ AD, float* __restrict__ es, float* __restrict__ ed) {
    int t = blockIdx.x * blockDim.x + threadIdx.x;
    if (t >= NN * HEADS) return;
    int n = t >> 2, hd = t & 3;
    const float* hr = H + (size_t)n * 100 + hd * 25;
    const float* as = AS + hd * 25;
    const float* ad = AD + hd * 25;
    float s1 = 0.f, s2 = 0.f;
    #pragma unroll
    for (int d = 0; d < 25; d++) {
        float v = hr[d];
        s1 += v * as[d];
        s2 += v * ad[d];
    }
    es[t] = s1;
    ed[t] = s2;
}

// ---------------- fused attention aggregate: softmax stats + weighted gather ----------------
// one wave per node (4 waves/block).
// pass 1: lane = edge_slot(16) x head(4); online (m,s); butterfly over slot bits.
// pass 2: half-wave h2 = lane>>5 handles edge e+h2; 25 lanes x float4 = 400B row;
//         weights computed on the fly; combine halves via shfl_xor(32).
__global__ __launch_bounds__(256) void k_attn(const float* __restrict__ H,
                                              const float* __restrict__ es,
                                              const float* __restrict__ ed,
                                              const int* __restrict__ offs,
                                              const int* __restrict__ csr,
                                              const float* __restrict__ bias,
                                              float* __restrict__ out) {
    const int wid = threadIdx.x >> 6;
    const int lane = threadIdx.x & 63;
    const int n = blockIdx.x * 4 + wid;
    if (n >= NN) return;
    const int beg = offs[n], end = offs[n + 1];

    // ---- pass 1: per-head softmax stats ----
    {
        const int el = lane >> 2, hd = lane & 3;
        float edh = ed[n * 4 + hd];
        float m = NEG_INF, s = 0.f;
        for (int e = beg + el; e < end; e += 16) {
            int si = csr[e];
            float a = es[si * 4 + hd] + edh;
            a = fmaxf(a, 0.2f * a);
            float nm = fmaxf(m, a);
            float sc = __expf(m - nm);
            s = s * sc + __expf(a - nm);
            m = nm;
        }
        #pragma unroll
        for (int mask = 4; mask <= 32; mask <<= 1) {
            float mo = __shfl_xor(m, mask, 64);
            float so = __shfl_xor(s, mask, 64);
            float nm = fmaxf(m, mo);
            float f1 = (m  > NEG_INF) ? __expf(m  - nm) : 0.f;
            float f2 = (mo > NEG_INF) ? __expf(mo - nm) : 0.f;
            s = s * f1 + so * f2;
            m = nm;
        }
        // stash per-head stats in lanes 0..3; broadcast below via __shfl
        // (fallthrough: m,s in registers; every lane's (m,s) is final for its head)
        // broadcast all four heads to every lane:
        float m0 = __shfl(m, 0, 64), m1 = __shfl(m, 1, 64);
        float m2 = __shfl(m, 2, 64), m3 = __shfl(m, 3, 64);
        float s0 = __shfl(s, 0, 64), s1 = __shfl(s, 1, 64);
        float s2 = __shfl(s, 2, 64), s3 = __shfl(s, 3, 64);

        // ---- pass 2 ----
        const int h2 = lane >> 5;        // which edge of the pair
        const int q  = lane & 31;        // 0..31, 25 active
        const int d0 = q * 4;
        const bool act = (q < 25);
        // per-lane loop-invariant head bookkeeping
        const int hdA = d0 / 25;
        const int hdB = (d0 + 3) / 25;
        const bool selA1 = ((d0 + 1) / 25) == hdA;
        const bool selA2 = ((d0 + 2) / 25) == hdA;
        float4 ed4 = *reinterpret_cast<const float4*>(&ed[n * 4]);
        auto pick = [&](int h, float v0, float v1, float v2, float v3) {
            return h == 0 ? v0 : (h == 1 ? v1 : (h == 2 ? v2 : v3));
        };
        const float edA = pick(hdA, ed4.x, ed4.y, ed4.z, ed4.w);
        const float edB = pick(hdB, ed4.x, ed4.y, ed4.z, ed4.w);
        const float mA  = pick(hdA, m0, m1, m2, m3);
        const float mB  = pick(hdB, m0, m1, m2, m3);
        const float iA  = 1.f / (pick(hdA, s0, s1, s2, s3) + 1e-16f);
        const float iB  = 1.f / (pick(hdB, s0, s1, s2, s3) + 1e-16f);

        float ax = 0.f, ay = 0.f, az = 0.f, aw = 0.f;
        for (int e0 = beg; e0 < end; e0 += 8) {
            #pragma unroll
            for (int u = 0; u < 4; ++u) {
                int ee = e0 + u * 2 + h2;
                bool valid = (ee < end);
                int ec = valid ? ee : beg;
                int si = csr[ec];
                float4 e4 = *reinterpret_cast<const float4*>(&es[si * 4]);
                float eAv = pick(hdA, e4.x, e4.y, e4.z, e4.w);
                float eBv = pick(hdB, e4.x, e4.y, e4.z, e4.w);
                float aA = eAv + edA; aA = fmaxf(aA, 0.2f * aA);
                float aB = eBv + edB; aB = fmaxf(aB, 0.2f * aB);
                float wA = __expf(aA - mA) * iA;
                float wB = __expf(aB - mB) * iB;
                if (!valid) { wA = 0.f; wB = 0.f; }
                float w1 = selA1 ? wA : wB;
                float w2 = selA2 ? wA : wB;
                if (act) {
                    float4 xv = *reinterpret_cast<const float4*>(&H[(size_t)si * 100 + d0]);
                    ax += wA * xv.x;
                    ay += w1 * xv.y;
                    az += w2 * xv.z;
                    aw += wB * xv.w;
                }
            }
        }
        // combine the two half-wave edge subsets
        ax += __shfl_xor(ax, 32, 64);
        ay += __shfl_xor(ay, 32, 64);
        az += __shfl_xor(az, 32, 64);
        aw += __shfl_xor(aw, 32, 64);
        if (act && h2 == 0) {
            float4 b = *reinterpret_cast<const float4*>(&bias[d0]);
            float4 o = {fmaxf(ax + b.x, 0.f), fmaxf(ay + b.y, 0.f),
                        fmaxf(az + b.z, 0.f), fmaxf(aw + b.w, 0.f)};
            *reinterpret_cast<float4*>(&out[(size_t)n * 100 + d0]) = o;
        }
    }
}

// ---------------- global max pool (2-level) ----------------
__global__ void k_pool1(const float* __restrict__ NE, const int* __restrict__ gstart,
                        float* __restrict__ part) {
    int g = blockIdx.x >> 3, c = blockIdx.x & 7;
    int d = threadIdx.x;
    if (d >= 100) return;
    int s0 = gstart[g], s1 = gstart[g + 1];
    int len = s1 - s0;
    int n0 = s0 + (int)((long long)len * c / 8);
    int n1 = s0 + (int)((long long)len * (c + 1) / 8);
    float vm = NEG_INF;
    for (int n = n0; n < n1; n++) vm = fmaxf(vm, NE[(size_t)n * 100 + d]);
    part[(size_t)(g * 8 + c) * 100 + d] = vm;
}

__global__ void k_pool2(const float* __restrict__ part, float* __restrict__ GE) {
    int g = blockIdx.x;
    int d = threadIdx.x;
    if (d >= 100) return;
    float vm = NEG_INF;
    for (int c = 0; c < 8; c++) vm = fmaxf(vm, part[(size_t)(g * 8 + c) * 100 + d]);
    GE[(size_t)g * 100 + d] = vm;
}

// ---------------- prototype head ----------------
__global__ void k_head(const float* __restrict__ GE, const float* __restrict__ P,
                       const float* __restrict__ LW, float* __restrict__ logits,
                       float* __restrict__ probs, float* __restrict__ dist) {
    int g = blockIdx.x;
    __shared__ float ge[100];
    __shared__ float sims[NUM_PROT];
    __shared__ float lg[OUT_DIM];
    int t = threadIdx.x;
    if (t < 100) ge[t] = GE[(size_t)g * 100 + t];
    __syncthreads();
    if (t < NUM_PROT) {
        float dot = 0.f, pn = 0.f, gn = 0.f;
        for (int d = 0; d < 100; d++) {
            float pv = P[t * 100 + d];
            float gv = ge[d];
            dot += gv * pv;
            pn += pv * pv;
            gn += gv * gv;
        }
        float ds = gn - 2.f * dot + pn;
        dist[g * NUM_PROT + t] = ds;
        sims[t] = logf((ds + 1.f) / (ds + 1e-4f));
    }
    __syncthreads();
    if (t < OUT_DIM) {
        float l = 0.f;
        for (int p = 0; p < NUM_PROT; p++) l += sims[p] * LW[t * NUM_PROT + p];
        lg[t] = l;
        logits[g * OUT_DIM + t] = l;
    }
    __syncthreads();
    if (t == 0) {
        float mm = fmaxf(lg[0], lg[1]);
        float e0 = __expf(lg[0] - mm), e1 = __expf(lg[1] - mm);
        float inv = 1.f / (e0 + e1);
        probs[g * OUT_DIM + 0] = e0 * inv;
        probs[g * OUT_DIM + 1] = e1 * inv;
    }
}

extern "C" void kernel_launch(void* const* d_in, const int* in_sizes, int n_in,
                              void* d_out, int out_size, void* d_ws, size_t ws_size,
                              hipStream_t stream) {
    const float* x     = (const float*)d_in[0];
    const int*   ei    = (const int*)d_in[1];
    const int*   batch = (const int*)d_in[2];
    const float* Wm[3]  = {(const float*)d_in[3],  (const float*)d_in[7],  (const float*)d_in[11]};
    const float* ASm[3] = {(const float*)d_in[4],  (const float*)d_in[8],  (const float*)d_in[12]};
    const float* ADm[3] = {(const float*)d_in[5],  (const float*)d_in[9],  (const float*)d_in[13]};
    const float* Bm[3]  = {(const float*)d_in[6],  (const float*)d_in[10], (const float*)d_in[14]};
    const float* P  = (const float*)d_in[15];
    const float* LW = (const float*)d_in[16];

    float* out = (float*)d_out;
    float* logits  = out;                                   // [64,2]
    float* probs   = out + GG * OUT_DIM;                    // [64,2]
    float* nodeEmb = out + 2 * GG * OUT_DIM;                // [N,100]
    float* GE      = nodeEmb + (size_t)NN * DENSE;          // [64,100]
    float* disto   = GE + GG * DENSE;                       // [64,10]

    // workspace carve-up
    char* w = (char*)d_ws;
    size_t off = 0;
    auto carve = [&](size_t bytes) -> void* {
        void* p = w + off;
        off += (bytes + 15) & ~(size_t)15;
        return p;
    };
    float* hA   = (float*)carve((size_t)NN * DENSE * 4);
    float* es   = (float*)carve((size_t)NN * HEADS * 4);
    float* ed   = (float*)carve((size_t)NN * HEADS * 4);
    int* cnt    = (int*)carve((size_t)NN * 4);
    int* offs   = (int*)carve((size_t)(NN + 1) * 4);
    int* pos    = (int*)carve((size_t)ETOT * 4);
    int* csr    = (int*)carve((size_t)ETOT * 4);
    int* csum   = (int*)carve((size_t)(NCHUNK + 1) * 4);
    int* gstart = (int*)carve((size_t)(GG + 1) * 4);
    float* part = (float*)carve((size_t)GG * 8 * DENSE * 4);
    (void)in_sizes; (void)n_in; (void)out_size; (void)ws_size;

    // ---- CSR build (once, reused for all 3 layers) ----
    hipMemsetAsync(cnt, 0, (size_t)NN * 4, stream);
    k_count<<<(ETOT + 255) / 256, 256, 0, stream>>>(ei, cnt, pos);
    k_scan1<<<NCHUNK, 256, 0, stream>>>(cnt, csum);
    k_scan2<<<1, 256, 0, stream>>>(csum);
    k_scan3<<<NCHUNK, 256, 0, stream>>>(cnt, csum, offs);
    k_scatter<<<(ETOT + 255) / 256, 256, 0, stream>>>(ei, offs, pos, csr);
    k_bounds<<<(NN + 255) / 256, 256, 0, stream>>>(batch, gstart);

    const int gemmGrid = (NN + 127) / 128;
    const int esedGrid = (NN * HEADS + 255) / 256;
    const int attnGrid = (NN + 3) / 4;

    const float* layerIn = x;
    for (int l = 0; l < 3; ++l) {
        if (l == 0) k_gemm<IN_DIM, 32><<<gemmGrid, 256, 0, stream>>>(layerIn, Wm[l], hA);
        else        k_gemm<DENSE,  20><<<gemmGrid, 256, 0, stream>>>(layerIn, Wm[l], hA);
        k_esed<<<esedGrid, 256, 0, stream>>>(hA, ASm[l], ADm[l], es, ed);
        k_attn<<<attnGrid, 256, 0, stream>>>(hA, es, ed, offs, csr, Bm[l], nodeEmb);
        layerIn = nodeEmb;
    }

    // ---- pooling ----
    k_pool1<<<GG * 8, 128, 0, stream>>>(nodeEmb, gstart, part);
    k_pool2<<<GG, 128, 0, stream>>>(part, GE);

    // ---- prototype head ----
    k_head<<<GG, 128, 0, stream>>>(GE, P, LW, logits, probs, disto);
}

// Round 6
// 507.195 us; speedup vs baseline: 1.0287x; 1.0287x over previous
//
#include <hip/hip_runtime.h>
#include <hip/hip_bf16.h>

#define NN      50000
#define EE      800000
#define ETOT    (EE + NN)        // + self loops
#define GG      64
#define HEADS   4
#define HID     25
#define DENSE   100
#define IN_DIM  128
#define OUT_DIM 2
#define NPC     5
#define NUM_PROT (OUT_DIM * NPC)
#define NCHUNK  ((NN + 255) / 256)

#define NEG_INF (-3.402823466e38f)

// ---------------- CSR build ----------------
__global__ void k_count(const int* __restrict__ ei, int* __restrict__ cnt, int* __restrict__ pos) {
    int e = blockIdx.x * blockDim.x + threadIdx.x;
    if (e >= ETOT) return;
    int dst = (e < EE) ? ei[EE + e] : (e - EE);
    pos[e] = atomicAdd(&cnt[dst], 1);
}

__global__ void k_scan1(const int* __restrict__ cnt, int* __restrict__ csum) {
    __shared__ int sh[256];
    int i = blockIdx.x * 256 + threadIdx.x;
    int v = (i < NN) ? cnt[i] : 0;
    sh[threadIdx.x] = v;
    __syncthreads();
    for (int s = 128; s > 0; s >>= 1) {
        if (threadIdx.x < s) sh[threadIdx.x] += sh[threadIdx.x + s];
        __syncthreads();
    }
    if (threadIdx.x == 0) csum[blockIdx.x] = sh[0];
}

__global__ void k_scan2(int* __restrict__ csum) {
    __shared__ int sh[256];
    int tid = threadIdx.x;
    int v = (tid < NCHUNK) ? csum[tid] : 0;
    sh[tid] = v;
    __syncthreads();
    for (int s = 1; s < 256; s <<= 1) {
        int t = (tid >= s) ? sh[tid - s] : 0;
        __syncthreads();
        sh[tid] += t;
        __syncthreads();
    }
    if (tid < NCHUNK) csum[tid] = sh[tid] - v;     // exclusive
    if (tid == NCHUNK) csum[NCHUNK] = sh[255];     // total
}

__global__ void k_scan3(const int* __restrict__ cnt, const int* __restrict__ csum, int* __restrict__ offs) {
    __shared__ int sh[256];
    int i = blockIdx.x * 256 + threadIdx.x;
    int v = (i < NN) ? cnt[i] : 0;
    sh[threadIdx.x] = v;
    __syncthreads();
    for (int s = 1; s < 256; s <<= 1) {
        int t = (threadIdx.x >= s) ? sh[threadIdx.x - s] : 0;
        __syncthreads();
        sh[threadIdx.x] += t;
        __syncthreads();
    }
    int excl = sh[threadIdx.x] - v + csum[blockIdx.x];
    if (i <= NN) offs[i] = excl;
}

__global__ void k_scatter(const int* __restrict__ ei, const int* __restrict__ offs,
                          const int* __restrict__ pos, int* __restrict__ csr) {
    int e = blockIdx.x * blockDim.x + threadIdx.x;
    if (e >= ETOT) return;
    int src, dst;
    if (e < EE) { src = ei[e]; dst = ei[EE + e]; }
    else        { src = dst = e - EE; }
    csr[offs[dst] + pos[e]] = src;
}

// ---------------- graph boundaries (batch is sorted) ----------------
__global__ void k_bounds(const int* __restrict__ batch, int* __restrict__ gstart) {
    int n = blockIdx.x * blockDim.x + threadIdx.x;
    if (n >= NN) return;
    int b = batch[n];
    if (n == 0) {
        for (int g = 0; g <= b; g++) gstart[g] = 0;
    } else {
        int pb = batch[n - 1];
        for (int g = pb + 1; g <= b; g++) gstart[g] = n;
    }
    if (n == NN - 1) {
        for (int g = b + 1; g <= GG; g++) gstart[g] = NN;
    }
}

// ---------------- GEMM: H = X @ W  ([N,DIN] x [DIN,100]) ----------------
// 256 threads, 128 rows/block, 16 rows x 4 cols per thread.
template <int DIN, int KC>
__global__ __launch_bounds__(256) void k_gemm(const float* __restrict__ X,
                                              const float* __restrict__ W,
                                              float* __restrict__ H) {
    constexpr int XSTR = KC + 4;          // row stride in floats (16B-aligned, bank-skewed)
    __shared__ float Ws[KC * 104];        // pad 100 -> 104
    __shared__ float Xs[128 * XSTR];
    const int tid = threadIdx.x;
    const int rl = tid >> 5;    // 0..7  -> rows rl*16 .. rl*16+15
    const int cg = tid & 31;    // 0..31 (25 active)
    const int node0 = blockIdx.x * 128;

    float acc[16][4] = {};
    constexpr int NCH = DIN / KC;         // exact: 128/32, 100/20
    constexpr int KQ = KC / 4;
    for (int kb = 0; kb < NCH; ++kb) {
        const int k0 = kb * KC;
        for (int idx = tid; idx < KC * 100; idx += 256) {
            int k = idx / 100, c = idx - k * 100;
            Ws[k * 104 + c] = W[(k0 + k) * 100 + c];
        }
        for (int q = tid; q < 128 * KQ; q += 256) {
            int r = q / KQ, kq = q - r * KQ;
            int row = node0 + r;
            float4 v = {0.f, 0.f, 0.f, 0.f};
            if (row < NN) v = *reinterpret_cast<const float4*>(&X[(size_t)row * DIN + k0 + kq * 4]);
            *reinterpret_cast<float4*>(&Xs[r * XSTR + kq * 4]) = v;
        }
        __syncthreads();
        if (cg < 25) {
            for (int kq = 0; kq < KQ; ++kq) {
                float4 w0 = *reinterpret_cast<const float4*>(&Ws[(kq * 4 + 0) * 104 + cg * 4]);
                float4 w1 = *reinterpret_cast<const float4*>(&Ws[(kq * 4 + 1) * 104 + cg * 4]);
                float4 w2 = *reinterpret_cast<const float4*>(&Ws[(kq * 4 + 2) * 104 + cg * 4]);
                float4 w3 = *reinterpret_cast<const float4*>(&Ws[(kq * 4 + 3) * 104 + cg * 4]);
                #pragma unroll
                for (int j = 0; j < 16; ++j) {
                    float4 xv = *reinterpret_cast<const float4*>(&Xs[(rl * 16 + j) * XSTR + kq * 4]);
                    acc[j][0] += xv.x * w0.x; acc[j][1] += xv.x * w0.y;
                    acc[j][2] += xv.x * w0.z; acc[j][3] += xv.x * w0.w;
                    acc[j][0] += xv.y * w1.x; acc[j][1] += xv.y * w1.y;
                    acc[j][2] += xv.y * w1.z; acc[j][3] += xv.y * w1.w;
                    acc[j][0] += xv.z * w2.x; acc[j][1] += xv.z * w2.y;
                    acc[j][2] += xv.z * w2.z; acc[j][3] += xv.z * w2.w;
                    acc[j][0] += xv.w * w3.x; acc[j][1] += xv.w * w3.y;
                    acc[j][2] += xv.w * w3.z; acc[j][3] += xv.w * w3.w;
                }
            }
        }
        __syncthreads();
    }
    if (cg < 25) {
        #pragma unroll
        for (int j = 0; j < 16; ++j) {
            int row = node0 + rl * 16 + j;
            if (row < NN) {
                float4 v = {acc[j][0], acc[j][1], acc[j][2], acc[j][3]};
                *reinterpret_cast<float4*>(&H[(size_t)row * 100 + cg * 4]) = v;
            }
        }
    }
}

// ---------------- per-node attention logits: es/ed ----------------
__global__ void k_esed(const float* __restrict__ H, const float* __restrict__ AS,
                       const float* __restrict__ AD, float* __restrict__ es, float* __restrict__ ed) {
    int t = blockIdx.x * blockDim.x + threadIdx.x;
    if (t >= NN * HEADS) return;
    int n = t >> 2, hd = t & 3;
    const float* hr = H + (size_t)n * 100 + hd * 25;
    const float* as = AS + hd * 25;
    const float* ad = AD + hd * 25;
    float s1 = 0.f, s2 = 0.f;
    #pragma unroll
    for (int d = 0; d < 25; d++) {
        float v = hr[d];
        s1 += v * as[d];
        s2 += v * ad[d];
    }
    es[t] = s1;
    ed[t] = s2;
}

// ---------------- phase A: per-node softmax stats + per-edge weights ----------------
// one wave per node; lane = edge_slot(16) * 4 + head(4); weights computed ONCE per edge.
__global__ __launch_bounds__(256) void k_msum(const float* __restrict__ es,
                                              const float* __restrict__ ed,
                                              const int* __restrict__ offs,
                                              const int* __restrict__ csr,
                                              float* __restrict__ wv) {
    int wid = threadIdx.x >> 6;
    int lane = threadIdx.x & 63;
    int n = blockIdx.x * 4 + wid;
    if (n >= NN) return;
    int el = lane >> 2, hd = lane & 3;
    int beg = offs[n], end = offs[n + 1];
    float edh = ed[n * 4 + hd];
    float m = NEG_INF, s = 0.f;
    for (int e = beg + el; e < end; e += 16) {
        int si = csr[e];
        float a = es[si * 4 + hd] + edh;
        a = (a > 0.f) ? a : 0.2f * a;
        float nm = fmaxf(m, a);
        float sc = __expf(m - nm);       // m=-inf, nm finite -> 0, no NaN
        s = s * sc + __expf(a - nm);
        m = nm;
    }
    // butterfly merge over edge-slot bits (lane bits 2..5)
    #pragma unroll
    for (int mask = 4; mask <= 32; mask <<= 1) {
        float mo = __shfl_xor(m, mask, 64);
        float so = __shfl_xor(s, mask, 64);
        float nm = fmaxf(m, mo);
        float f1 = (m  > NEG_INF) ? __expf(m  - nm) : 0.f;
        float f2 = (mo > NEG_INF) ? __expf(mo - nm) : 0.f;
        s = s * f1 + so * f2;
        m = nm;
    }
    float invs = 1.f / (s + 1e-16f);
    // fused weight pass (coalesced 256B writes per 16 edges)
    for (int e = beg + el; e < end; e += 16) {
        int si = csr[e];
        float a = es[si * 4 + hd] + edh;
        a = (a > 0.f) ? a : 0.2f * a;
        wv[(size_t)e * 4 + hd] = __expf(a - m) * invs;
    }
}

// ---------------- phase B: weighted gather-accumulate ----------------
// one wave per node (4 waves/block). Half-wave h2 handles edge e+h2:
// 25 lanes x float4 = one 400B row per wave-instruction fetches TWO edges' rows.
// wv read as one broadcast float4; component head-select precomputed per lane.
__global__ __launch_bounds__(256) void k_acc(const float* __restrict__ H,
                                             const float* __restrict__ wv,
                                             const int* __restrict__ offs,
                                             const int* __restrict__ csr,
                                             const float* __restrict__ bias,
                                             float* __restrict__ out) {
    const int wid = threadIdx.x >> 6;
    const int lane = threadIdx.x & 63;
    const int n = blockIdx.x * 4 + wid;
    if (n >= NN) return;
    const int beg = offs[n], end = offs[n + 1];

    const int h2 = lane >> 5;        // which edge of the pair
    const int q  = lane & 31;        // 0..31, 25 active
    const int d0 = q * 4;
    const bool act = (q < 25);
    // loop-invariant per-lane head bookkeeping (d0..d0+3 straddle at most 2 heads)
    const int hdA = d0 / 25;
    const int hdB = (d0 + 3) / 25;
    const bool selA1 = ((d0 + 1) / 25) == hdA;
    const bool selA2 = ((d0 + 2) / 25) == hdA;
    auto pick = [](int h, const float4& v) {
        return h == 0 ? v.x : (h == 1 ? v.y : (h == 2 ? v.z : v.w));
    };

    float ax = 0.f, ay = 0.f, az = 0.f, aw = 0.f;
    for (int e0 = beg; e0 < end; e0 += 8) {
        #pragma unroll
        for (int u = 0; u < 4; ++u) {
            int ee = e0 + u * 2 + h2;
            bool valid = (ee < end);
            int ec = valid ? ee : beg;
            int si = csr[ec];
            float4 w4 = *reinterpret_cast<const float4*>(&wv[(size_t)ec * 4]);
            float wA = pick(hdA, w4);
            float wB = pick(hdB, w4);
            if (!valid) { wA = 0.f; wB = 0.f; }
            float w1 = selA1 ? wA : wB;
            float w2 = selA2 ? wA : wB;
            if (act) {
                float4 xv = *reinterpret_cast<const float4*>(&H[(size_t)si * 100 + d0]);
                ax += wA * xv.x;
                ay += w1 * xv.y;
                az += w2 * xv.z;
                aw += wB * xv.w;
            }
        }
    }
    // combine the two half-wave edge subsets
    ax += __shfl_xor(ax, 32, 64);
    ay += __shfl_xor(ay, 32, 64);
    az += __shfl_xor(az, 32, 64);
    aw += __shfl_xor(aw, 32, 64);
    if (act && h2 == 0) {
        float4 b = *reinterpret_cast<const float4*>(&bias[d0]);
        float4 o = {fmaxf(ax + b.x, 0.f), fmaxf(ay + b.y, 0.f),
                    fmaxf(az + b.z, 0.f), fmaxf(aw + b.w, 0.f)};
        *reinterpret_cast<float4*>(&out[(size_t)n * 100 + d0]) = o;
    }
}

// ---------------- global max pool (2-level) ----------------
__global__ void k_pool1(const float* __restrict__ NE, const int* __restrict__ gstart,
                        float* __restrict__ part) {
    int g = blockIdx.x >> 3, c = blockIdx.x & 7;
    int d = threadIdx.x;
    if (d >= 100) return;
    int s0 = gstart[g], s1 = gstart[g + 1];
    int len = s1 - s0;
    int n0 = s0 + (int)((long long)len * c / 8);
    int n1 = s0 + (int)((long long)len * (c + 1) / 8);
    float vm = NEG_INF;
    for (int n = n0; n < n1; n++) vm = fmaxf(vm, NE[(size_t)n * 100 + d]);
    part[(size_t)(g * 8 + c) * 100 + d] = vm;
}

__global__ void k_pool2(const float* __restrict__ part, float* __restrict__ GE) {
    int g = blockIdx.x;
    int d = threadIdx.x;
    if (d >= 100) return;
    float vm = NEG_INF;
    for (int c = 0; c < 8; c++) vm = fmaxf(vm, part[(size_t)(g * 8 + c) * 100 + d]);
    GE[(size_t)g * 100 + d] = vm;
}

// ---------------- prototype head ----------------
__global__ void k_head(const float* __restrict__ GE, const float* __restrict__ P,
                       const float* __restrict__ LW, float* __restrict__ logits,
                       float* __restrict__ probs, float* __restrict__ dist) {
    int g = blockIdx.x;
    __shared__ float ge[100];
    __shared__ float sims[NUM_PROT];
    __shared__ float lg[OUT_DIM];
    int t = threadIdx.x;
    if (t < 100) ge[t] = GE[(size_t)g * 100 + t];
    __syncthreads();
    if (t < NUM_PROT) {
        float dot = 0.f, pn = 0.f, gn = 0.f;
        for (int d = 0; d < 100; d++) {
            float pv = P[t * 100 + d];
            float gv = ge[d];
            dot += gv * pv;
            pn += pv * pv;
            gn += gv * gv;
        }
        float ds = gn - 2.f * dot + pn;
        dist[g * NUM_PROT + t] = ds;
        sims[t] = logf((ds + 1.f) / (ds + 1e-4f));
    }
    __syncthreads();
    if (t < OUT_DIM) {
        float l = 0.f;
        for (int p = 0; p < NUM_PROT; p++) l += sims[p] * LW[t * NUM_PROT + p];
        lg[t] = l;
        logits[g * OUT_DIM + t] = l;
    }
    __syncthreads();
    if (t == 0) {
        float mm = fmaxf(lg[0], lg[1]);
        float e0 = __expf(lg[0] - mm), e1 = __expf(lg[1] - mm);
        float inv = 1.f / (e0 + e1);
        probs[g * OUT_DIM + 0] = e0 * inv;
        probs[g * OUT_DIM + 1] = e1 * inv;
    }
}

extern "C" void kernel_launch(void* const* d_in, const int* in_sizes, int n_in,
                              void* d_out, int out_size, void* d_ws, size_t ws_size,
                              hipStream_t stream) {
    const float* x     = (const float*)d_in[0];
    const int*   ei    = (const int*)d_in[1];
    const int*   batch = (const int*)d_in[2];
    const float* Wm[3]  = {(const float*)d_in[3],  (const float*)d_in[7],  (const float*)d_in[11]};
    const float* ASm[3] = {(const float*)d_in[4],  (const float*)d_in[8],  (const float*)d_in[12]};
    const float* ADm[3] = {(const float*)d_in[5],  (const float*)d_in[9],  (const float*)d_in[13]};
    const float* Bm[3]  = {(const float*)d_in[6],  (const float*)d_in[10], (const float*)d_in[14]};
    const float* P  = (const float*)d_in[15];
    const float* LW = (const float*)d_in[16];

    float* out = (float*)d_out;
    float* logits  = out;                                   // [64,2]
    float* probs   = out + GG * OUT_DIM;                    // [64,2]
    float* nodeEmb = out + 2 * GG * OUT_DIM;                // [N,100]
    float* GE      = nodeEmb + (size_t)NN * DENSE;          // [64,100]
    float* disto   = GE + GG * DENSE;                       // [64,10]

    // workspace carve-up
    char* w = (char*)d_ws;
    size_t off = 0;
    auto carve = [&](size_t bytes) -> void* {
        void* p = w + off;
        off += (bytes + 15) & ~(size_t)15;
        return p;
    };
    float* hA   = (float*)carve((size_t)NN * DENSE * 4);
    float* es   = (float*)carve((size_t)NN * HEADS * 4);
    float* ed   = (float*)carve((size_t)NN * HEADS * 4);
    int* cnt    = (int*)carve((size_t)NN * 4);
    int* offs   = (int*)carve((size_t)(NN + 1) * 4);
    int* pos    = (int*)carve((size_t)ETOT * 4);
    int* csr    = (int*)carve((size_t)ETOT * 4);
    int* csum   = (int*)carve((size_t)(NCHUNK + 1) * 4);
    int* gstart = (int*)carve((size_t)(GG + 1) * 4);
    float* part = (float*)carve((size_t)GG * 8 * DENSE * 4);
    float* wv   = (float*)carve((size_t)ETOT * HEADS * 4);   // per-edge weights
    (void)in_sizes; (void)n_in; (void)out_size; (void)ws_size;

    // ---- CSR build (once, reused for all 3 layers) ----
    hipMemsetAsync(cnt, 0, (size_t)NN * 4, stream);
    k_count<<<(ETOT + 255) / 256, 256, 0, stream>>>(ei, cnt, pos);
    k_scan1<<<NCHUNK, 256, 0, stream>>>(cnt, csum);
    k_scan2<<<1, 256, 0, stream>>>(csum);
    k_scan3<<<NCHUNK, 256, 0, stream>>>(cnt, csum, offs);
    k_scatter<<<(ETOT + 255) / 256, 256, 0, stream>>>(ei, offs, pos, csr);
    k_bounds<<<(NN + 255) / 256, 256, 0, stream>>>(batch, gstart);

    const int gemmGrid = (NN + 127) / 128;
    const int esedGrid = (NN * HEADS + 255) / 256;
    const int msumGrid = (NN + 3) / 4;
    const int accGrid  = (NN + 3) / 4;

    const float* layerIn = x;
    for (int l = 0; l < 3; ++l) {
        if (l == 0) k_gemm<IN_DIM, 32><<<gemmGrid, 256, 0, stream>>>(layerIn, Wm[l], hA);
        else        k_gemm<DENSE,  20><<<gemmGrid, 256, 0, stream>>>(layerIn, Wm[l], hA);
        k_esed<<<esedGrid, 256, 0, stream>>>(hA, ASm[l], ADm[l], es, ed);
        k_msum<<<msumGrid, 256, 0, stream>>>(es, ed, offs, csr, wv);
        k_acc<<<accGrid, 256, 0, stream>>>(hA, wv, offs, csr, Bm[l], nodeEmb);
        layerIn = nodeEmb;
    }

    // ---- pooling ----
    k_pool1<<<GG * 8, 128, 0, stream>>>(nodeEmb, gstart, part);
    k_pool2<<<GG, 128, 0, stream>>>(part, GE);

    // ---- prototype head ----
    k_head<<<GG, 128, 0, stream>>>(GE, P, LW, logits, probs, disto);
}